// Round 8
// baseline (65.481 us; speedup 1.0000x reference)
//
#include <hip/hip_runtime.h>
#include <hip/hip_bf16.h>

// Causal attention, B=2 H=16 S=2048 D=64, fp32 in/out.
// R8 = R7 + flash-decoding KV-split (chunks of 16 tiles; qt>=16 -> 2 chunks
// with fp32 partials in ws + combine kernel) to lift grid-limited occupancy
// (1024 -> 1536 blocks), + hoisted LDS fragment addresses.
// Swapped QK^T, in-register softmax (exp2, defer-max), permuted-V^T PV
// (zero-conflict b128), permlane reductions, setprio, 2-phase double buffer.

typedef __attribute__((ext_vector_type(8))) short bf16x8;
typedef __attribute__((ext_vector_type(4))) float f32x4;
typedef unsigned uint2v __attribute__((ext_vector_type(2)));

#define MFMA32K(a, b, c) __builtin_amdgcn_mfma_f32_16x16x32_bf16(a, b, c, 0, 0, 0)

constexpr int Bsz = 2, Hn = 16, Sn = 2048, Dn = 64;
constexpr int QBLK = 64, KBLK = 64;
constexpr int NE = Bsz * Hn * Sn * Dn;
constexpr int NPART = Bsz * Hn * 16 * 2;  // (bh, qt>=16) pairs x 2 chunks

__device__ inline short f2bf(float f) {
  union { float f; unsigned u; } v;
  v.f = f;
  unsigned r = v.u + 0x7FFF + ((v.u >> 16) & 1);  // RNE
  return (short)(r >> 16);
}

__device__ inline unsigned pk_bf16(float lo, float hi) {
  unsigned r;
  asm("v_cvt_pk_bf16_f32 %0, %1, %2" : "=v"(r) : "v"(lo), "v"(hi));
  return r;
}

__device__ inline void gl2lds16(const void* g, void* l) {
  __builtin_amdgcn_global_load_lds(
      (const __attribute__((address_space(1))) unsigned int*)g,
      (__attribute__((address_space(3))) unsigned int*)l, 16, 0, 0);
}

// tile rows = 128B; XOR 16B-slot index with row&7 (involution, both sides)
__device__ inline int swz(int row, int colbyte) {
  return row * 128 + (colbyte ^ ((row & 7) << 4));
}

#if defined(__has_builtin)
#if __has_builtin(__builtin_amdgcn_permlane16_swap) && \
    __has_builtin(__builtin_amdgcn_permlane32_swap)
#define HAVE_PERMLANE_SWAP 1
#endif
#endif

__device__ inline float xred_max(float x) {
#ifdef HAVE_PERMLANE_SWAP
  uint2v a = __builtin_amdgcn_permlane16_swap(__float_as_uint(x),
                                              __float_as_uint(x), false, false);
  x = fmaxf(__uint_as_float(a[0]), __uint_as_float(a[1]));
  uint2v b = __builtin_amdgcn_permlane32_swap(__float_as_uint(x),
                                              __float_as_uint(x), false, false);
  x = fmaxf(__uint_as_float(b[0]), __uint_as_float(b[1]));
#else
  x = fmaxf(x, __shfl_xor(x, 16, 64));
  x = fmaxf(x, __shfl_xor(x, 32, 64));
#endif
  return x;
}
__device__ inline float xred_sum(float x) {
#ifdef HAVE_PERMLANE_SWAP
  uint2v a = __builtin_amdgcn_permlane16_swap(__float_as_uint(x),
                                              __float_as_uint(x), false, false);
  x = __uint_as_float(a[0]) + __uint_as_float(a[1]);
  uint2v b = __builtin_amdgcn_permlane32_swap(__float_as_uint(x),
                                              __float_as_uint(x), false, false);
  x = __uint_as_float(b[0]) + __uint_as_float(b[1]);
#else
  x += __shfl_xor(x, 16, 64);
  x += __shfl_xor(x, 32, 64);
#endif
  return x;
}

// ------- prepass (merged): z=0: K fp32->bf16; z=1: V -> V^T bf16 -------
// V^T columns permuted within each 64-tile: position p holds element
// k(p) = 32*(p>>5) + 16*((p>>2)&1) + 4*((p>>3)&3) + (p&3), so the PV
// A-fragment {k=32t2+4g+i} u {k=32t2+16+4g+i} is contiguous 16B at p=32t2+8g.
__global__ __launch_bounds__(256) void prep(const float* __restrict__ K,
                                            const float* __restrict__ V,
                                            short* __restrict__ Kb,
                                            short* __restrict__ Vt) {
  const int tile = blockIdx.x, bh = blockIdx.y;
  const int tid = threadIdx.x;
  const int r = tid >> 2, c = (tid & 3) * 16;
  const size_t base = (size_t)bh * Sn * Dn;

  if (blockIdx.z == 0) {
    const float* kp = K + base + (size_t)(tile * 64 + r) * Dn + c;
    float4 x0 = *(const float4*)(kp + 0);
    float4 x1 = *(const float4*)(kp + 4);
    float4 x2 = *(const float4*)(kp + 8);
    float4 x3 = *(const float4*)(kp + 12);
    bf16x8 w0, w1;
    w0[0] = f2bf(x0.x); w0[1] = f2bf(x0.y); w0[2] = f2bf(x0.z); w0[3] = f2bf(x0.w);
    w0[4] = f2bf(x1.x); w0[5] = f2bf(x1.y); w0[6] = f2bf(x1.z); w0[7] = f2bf(x1.w);
    w1[0] = f2bf(x2.x); w1[1] = f2bf(x2.y); w1[2] = f2bf(x2.z); w1[3] = f2bf(x2.w);
    w1[4] = f2bf(x3.x); w1[5] = f2bf(x3.y); w1[6] = f2bf(x3.z); w1[7] = f2bf(x3.w);
    short* op = Kb + base + (size_t)(tile * 64 + r) * Dn + c;
    *(bf16x8*)op = w0;
    *(bf16x8*)(op + 8) = w1;
  } else {
    __shared__ short t[64][66];  // +2 pad
    const float* vp = V + base + (size_t)(tile * 64 + r) * Dn + c;
    float4 x0 = *(const float4*)(vp + 0);
    float4 x1 = *(const float4*)(vp + 4);
    float4 x2 = *(const float4*)(vp + 8);
    float4 x3 = *(const float4*)(vp + 12);
    short* tr = &t[r][c];
    tr[0] = f2bf(x0.x); tr[1] = f2bf(x0.y); tr[2] = f2bf(x0.z); tr[3] = f2bf(x0.w);
    tr[4] = f2bf(x1.x); tr[5] = f2bf(x1.y); tr[6] = f2bf(x1.z); tr[7] = f2bf(x1.w);
    tr[8] = f2bf(x2.x); tr[9] = f2bf(x2.y); tr[10] = f2bf(x2.z); tr[11] = f2bf(x2.w);
    tr[12] = f2bf(x3.x); tr[13] = f2bf(x3.y); tr[14] = f2bf(x3.z); tr[15] = f2bf(x3.w);
    __syncthreads();
    short* op = Vt + base + (size_t)r * Sn + tile * 64 + c;
    bf16x8 w0, w1;
#pragma unroll
    for (int j = 0; j < 8; ++j) {
      int p0 = c + j, p1 = c + 8 + j;
      int k0 = 32 * (p0 >> 5) + 16 * ((p0 >> 2) & 1) + 4 * ((p0 >> 3) & 3) + (p0 & 3);
      int k1 = 32 * (p1 >> 5) + 16 * ((p1 >> 2) & 1) + 4 * ((p1 >> 3) & 3) + (p1 & 3);
      w0[j] = t[k0][r];
      w1[j] = t[k1][r];
    }
    *(bf16x8*)op = w0;
    *(bf16x8*)(op + 8) = w1;
  }
}

// ---------------------------- main attention ----------------------------
// grid.y = 48 chunks, work-descending:
//   qy in [0,16):  qt = 31 - qy, chunk 0 (16 tiles)
//   qy in [16,32): qt = 47 - qy, chunk 1 (qt-15 tiles, 16..1)
//   qy in [32,48): qt = 47 - qy, chunk 0 (qt+1 tiles, 16..1) -> direct O
__global__ __launch_bounds__(256) void attn_fwd(
    const float* __restrict__ Q, const short* __restrict__ Kb,
    const short* __restrict__ Vt, const float* __restrict__ SF,
    float* __restrict__ O, float* __restrict__ Opart,
    float* __restrict__ MLpart) {
  __shared__ short Kbuf[2][64 * 64];   // [k][d] bf16, swizzled
  __shared__ short Vbuf[2][64 * 64];   // [d][p(k)] bf16, swizzled

  const int bh = blockIdx.x;
  const int qy = blockIdx.y;
  const int qt = (qy < 16) ? (31 - qy) : (47 - qy);
  const int chunk = (qy >= 16 && qy < 32) ? 1 : 0;
  const int t0 = chunk * 16;
  const int t1 = min(qt, t0 + 15);

  const int tid = threadIdx.x;
  const int wave = tid >> 6, lane = tid & 63;
  const int g = lane >> 4, lc = lane & 15;
  const float qscale = 1.4426950408889634f / SF[0];  // exp2 domain

  const size_t base = (size_t)bh * Sn * Dn;
  const short* Kbase = Kb + base;
  const short* Vtbase = Vt + base;
  const int qg = qt * QBLK + wave * 16 + lc;  // this lane's q row

  // hoisted per-lane fragment addresses (loop-invariant)
  int ka[4][2], va[2][4];
#pragma unroll
  for (int t = 0; t < 4; ++t) {
    ka[t][0] = swz(t * 16 + lc, g * 16);
    ka[t][1] = swz(t * 16 + lc, g * 16 + 64);
  }
#pragma unroll
  for (int t2 = 0; t2 < 2; ++t2)
#pragma unroll
    for (int dt = 0; dt < 4; ++dt)
      va[t2][dt] = swz(dt * 16 + lc, t2 * 64 + g * 16);
  // hoisted staging source offsets (within a tile)
  int koff[2], voff[2];
#pragma unroll
  for (int j = 0; j < 2; ++j) {
    int c = wave * 2 + j;
    int off = c * 1024 + lane * 16;
    int row = off >> 7;
    int col = (off & 127) ^ ((row & 7) << 4);
    koff[j] = row * 128 + col;
    voff[j] = row * (Sn * 2) + col;
  }

  auto stageK = [&](int kt2, int buf) {
    const char* gsrc = (const char*)Kbase + (size_t)kt2 * (KBLK * Dn * 2);
#pragma unroll
    for (int j = 0; j < 2; ++j)
      gl2lds16(gsrc + koff[j], (char*)Kbuf[buf] + (wave * 2 + j) * 1024);
  };
  auto stageV = [&](int kt2, int buf) {
    const char* gsrc = (const char*)Vtbase + (size_t)kt2 * (KBLK * 2);
#pragma unroll
    for (int j = 0; j < 2; ++j)
      gl2lds16(gsrc + voff[j], (char*)Vbuf[buf] + (wave * 2 + j) * 1024);
  };

  // ---- Q fragment (B operand): elem j = Q[qg][g*8+32h+j] * qscale ----
  bf16x8 bq[2];
  {
    const float* qp = Q + base + (size_t)qg * Dn + g * 8;
#pragma unroll
    for (int h = 0; h < 2; ++h) {
      float4 x0 = *(const float4*)(qp + 32 * h);
      float4 x1 = *(const float4*)(qp + 32 * h + 4);
      bf16x8 a;
      a[0] = f2bf(x0.x * qscale); a[1] = f2bf(x0.y * qscale);
      a[2] = f2bf(x0.z * qscale); a[3] = f2bf(x0.w * qscale);
      a[4] = f2bf(x1.x * qscale); a[5] = f2bf(x1.y * qscale);
      a[6] = f2bf(x1.z * qscale); a[7] = f2bf(x1.w * qscale);
      bq[h] = a;
    }
  }

  f32x4 o[4];
#pragma unroll
  for (int dt = 0; dt < 4; ++dt) o[dt] = (f32x4){0.f, 0.f, 0.f, 0.f};
  float m = -10000.0f, l = 0.f;  // finite sentinel

  int cur = 0;
  stageK(t0, 0);
  stageV(t0, 0);
  __syncthreads();

  for (int kt = t0; kt <= t1; ++kt) {
    if (kt < t1) { stageK(kt + 1, cur ^ 1); stageV(kt + 1, cur ^ 1); }

    const char* Kc = (const char*)Kbuf[cur];
    const char* Vc = (const char*)Vbuf[cur];

    // ---- swapped QK^T: s[t][i] = S[q=qg][k = kb+t*16+g*4+i] ----
    f32x4 s[4];
    __builtin_amdgcn_s_setprio(1);
#pragma unroll
    for (int t = 0; t < 4; ++t) {
      bf16x8 ak0 = *(const bf16x8*)(Kc + ka[t][0]);
      bf16x8 ak1 = *(const bf16x8*)(Kc + ka[t][1]);
      f32x4 z = (f32x4){0.f, 0.f, 0.f, 0.f};
      z = MFMA32K(ak0, bq[0], z);
      z = MFMA32K(ak1, bq[1], z);
      s[t] = z;
    }
    __builtin_amdgcn_s_setprio(0);

    if (kt == qt) {  // causal mask on diagonal tile only
      const int kb = kt * KBLK;
#pragma unroll
      for (int t = 0; t < 4; ++t)
#pragma unroll
        for (int i = 0; i < 4; ++i) {
          int kg = kb + t * 16 + g * 4 + i;
          if (kg > qg) s[t][i] = -30000.0f;
        }
    }

    // ---- in-register online softmax (exp2 domain), defer-max THR=8 ----
    float pmax = fmaxf(fmaxf(s[0][0], s[0][1]), fmaxf(s[0][2], s[0][3]));
#pragma unroll
    for (int t = 1; t < 4; ++t)
      pmax = fmaxf(pmax, fmaxf(fmaxf(s[t][0], s[t][1]),
                               fmaxf(s[t][2], s[t][3])));
    pmax = xred_max(pmax);
    if (!__all(pmax - m <= 8.0f)) {
      float mnew = fmaxf(m, pmax);
      float alpha = exp2f(m - mnew);
      l *= alpha;
#pragma unroll
      for (int dt = 0; dt < 4; ++dt) o[dt] *= alpha;
      m = mnew;
    }
    float rs = 0.f;
#pragma unroll
    for (int t = 0; t < 4; ++t)
#pragma unroll
      for (int i = 0; i < 4; ++i) {
        float p = exp2f(s[t][i] - m);
        s[t][i] = p;
        rs += p;
      }
    l += xred_sum(rs);

    // ---- PV: permuted V^T A-frag = one b128 (conflict-free) per (t2,dt) ----
    union { unsigned uu[4]; bf16x8 v; } pb[2];
#pragma unroll
    for (int t2 = 0; t2 < 2; ++t2) {
      pb[t2].uu[0] = pk_bf16(s[2 * t2][0], s[2 * t2][1]);
      pb[t2].uu[1] = pk_bf16(s[2 * t2][2], s[2 * t2][3]);
      pb[t2].uu[2] = pk_bf16(s[2 * t2 + 1][0], s[2 * t2 + 1][1]);
      pb[t2].uu[3] = pk_bf16(s[2 * t2 + 1][2], s[2 * t2 + 1][3]);
    }
    __builtin_amdgcn_s_setprio(1);
#pragma unroll
    for (int t2 = 0; t2 < 2; ++t2) {
#pragma unroll
      for (int dt = 0; dt < 4; ++dt) {
        bf16x8 av = *(const bf16x8*)(Vc + va[t2][dt]);
        o[dt] = MFMA32K(av, pb[t2].v, o[dt]);
      }
    }
    __builtin_amdgcn_s_setprio(0);

    __syncthreads();  // next tile landed (vmcnt) + cur fully consumed
    cur ^= 1;
  }

  if (qt < 16) {
    // single chunk: final output
    const float inv = 1.0f / l;
    float* op = O + base + (size_t)qg * Dn;
#pragma unroll
    for (int dt = 0; dt < 4; ++dt) {
      f32x4 r = o[dt] * inv;
      *(f32x4*)(op + dt * 16 + g * 4) = r;
    }
  } else {
    // partial: raw o, plus (m, l) per row
    const int p = (bh * 16 + (qt - 16)) * 2 + chunk;
    const int row = wave * 16 + lc;
    float* op = Opart + (size_t)p * 4096 + row * 64;
#pragma unroll
    for (int dt = 0; dt < 4; ++dt)
      *(f32x4*)(op + dt * 16 + g * 4) = o[dt];
    if (g == 0) ((float2*)MLpart)[p * 64 + row] = make_float2(m, l);
  }
}

// ---------------- combine: merge 2 partials for qt >= 16 ----------------
__global__ __launch_bounds__(256) void combine(const float* __restrict__ Opart,
                                               const float* __restrict__ MLpart,
                                               float* __restrict__ O) {
  const int bx = blockIdx.x;           // 0..511
  const int bh = bx >> 4, qh = bx & 15, qt = 16 + qh;
  const int p0 = (bh * 16 + qh) * 2;
  const int tid = threadIdx.x;
  const int r = tid >> 2, dc = (tid & 3) * 16;

  const float2 ml0 = ((const float2*)MLpart)[p0 * 64 + r];
  const float2 ml1 = ((const float2*)MLpart)[(p0 + 1) * 64 + r];
  const float M = fmaxf(ml0.x, ml1.x);
  const float s0 = exp2f(ml0.x - M), s1 = exp2f(ml1.x - M);
  const float inv = 1.0f / (ml0.y * s0 + ml1.y * s1);

  const float* a = Opart + (size_t)p0 * 4096 + r * 64 + dc;
  const float* b = a + 4096;
  float* op = O + (size_t)bh * Sn * Dn + (size_t)(qt * 64 + r) * Dn + dc;
#pragma unroll
  for (int j = 0; j < 4; ++j) {
    float4 x = *(const float4*)(a + j * 4);
    float4 y = *(const float4*)(b + j * 4);
    float4 z;
    z.x = (x.x * s0 + y.x * s1) * inv;
    z.y = (x.y * s0 + y.y * s1) * inv;
    z.z = (x.z * s0 + y.z * s1) * inv;
    z.w = (x.w * s0 + y.w * s1) * inv;
    *(float4*)(op + j * 4) = z;
  }
}

extern "C" void kernel_launch(void* const* d_in, const int* in_sizes, int n_in,
                              void* d_out, int out_size, void* d_ws, size_t ws_size,
                              hipStream_t stream) {
  const float* Q = (const float*)d_in[0];
  const float* K = (const float*)d_in[1];
  const float* V = (const float*)d_in[2];
  const float* SF = (const float*)d_in[3];
  // d_in[4] causal mask: tril by construction -> applied analytically (k<=q).
  float* O = (float*)d_out;

  short* Kb = (short*)d_ws;            // 8 MB  [B*H][2048][64] bf16
  short* Vt = Kb + NE;                 // 8 MB  [B*H][64][2048] bf16 (permuted)
  float* Opart = (float*)(Vt + NE);    // 16 MB [NPART][64][64] fp32
  float* MLpart = Opart + (size_t)NPART * 4096;  // 512 KB [NPART][64][2]

  prep<<<dim3(Sn / 64, Bsz * Hn, 2), 256, 0, stream>>>(K, V, Kb, Vt);
  attn_fwd<<<dim3(Bsz * Hn, 48), 256, 0, stream>>>(Q, Kb, Vt, SF, O, Opart,
                                                   MLpart);
  combine<<<dim3(Bsz * Hn * 16), 256, 0, stream>>>(Opart, MLpart, O);
}

// Round 9
// 50.345 us; speedup vs baseline: 1.3006x; 1.3006x over previous
//
#include <hip/hip_runtime.h>
#include <hip/hip_bf16.h>

// Causal attention, B=2 H=16 S=2048 D=64, fp32 in/out.
// R9 = R7 (single attn kernel, QBLK=64, 1024 blocks) +
//  (a) __launch_bounds__(256,4): 128-VGPR budget (grid caps residency at 4
//      blocks/CU anyway) -- stop compiler remat/refetch squeeze at VGPR=48,
//  (b) native v_exp_f32 via __builtin_amdgcn_exp2f (ocml wrapper was ~8x),
//  (c) l accumulated by MFMA with ones-column A-fragment (deletes sum tree
//      + xred_sum permlanes; numerically consistent with o's bf16 P),
//  (d) strength-reduced staging pointers.
// Swapped QK^T, in-register softmax (exp2, defer-max), permuted-V^T PV
// (zero-conflict b128), permlane max-reduce, setprio, 2-phase double buffer.

typedef __attribute__((ext_vector_type(8))) short bf16x8;
typedef __attribute__((ext_vector_type(4))) float f32x4;
typedef unsigned uint2v __attribute__((ext_vector_type(2)));

#define MFMA32K(a, b, c) __builtin_amdgcn_mfma_f32_16x16x32_bf16(a, b, c, 0, 0, 0)

constexpr int Bsz = 2, Hn = 16, Sn = 2048, Dn = 64;
constexpr int QBLK = 64, KBLK = 64;
constexpr int NE = Bsz * Hn * Sn * Dn;

#if defined(__has_builtin)
#if __has_builtin(__builtin_amdgcn_exp2f)
#define EXP2(x) __builtin_amdgcn_exp2f(x)
#endif
#endif
#ifndef EXP2
#define EXP2(x) exp2f(x)
#endif

__device__ inline short f2bf(float f) {
  union { float f; unsigned u; } v;
  v.f = f;
  unsigned r = v.u + 0x7FFF + ((v.u >> 16) & 1);  // RNE
  return (short)(r >> 16);
}

__device__ inline unsigned pk_bf16(float lo, float hi) {
  unsigned r;
  asm("v_cvt_pk_bf16_f32 %0, %1, %2" : "=v"(r) : "v"(lo), "v"(hi));
  return r;
}

__device__ inline void gl2lds16(const void* g, void* l) {
  __builtin_amdgcn_global_load_lds(
      (const __attribute__((address_space(1))) unsigned int*)g,
      (__attribute__((address_space(3))) unsigned int*)l, 16, 0, 0);
}

// tile rows = 128B; XOR 16B-slot index with row&7 (involution, both sides)
__device__ inline int swz(int row, int colbyte) {
  return row * 128 + (colbyte ^ ((row & 7) << 4));
}

#if defined(__has_builtin)
#if __has_builtin(__builtin_amdgcn_permlane16_swap) && \
    __has_builtin(__builtin_amdgcn_permlane32_swap)
#define HAVE_PERMLANE_SWAP 1
#endif
#endif

__device__ inline float xred_max(float x) {
#ifdef HAVE_PERMLANE_SWAP
  uint2v a = __builtin_amdgcn_permlane16_swap(__float_as_uint(x),
                                              __float_as_uint(x), false, false);
  x = fmaxf(__uint_as_float(a[0]), __uint_as_float(a[1]));
  uint2v b = __builtin_amdgcn_permlane32_swap(__float_as_uint(x),
                                              __float_as_uint(x), false, false);
  x = fmaxf(__uint_as_float(b[0]), __uint_as_float(b[1]));
#else
  x = fmaxf(x, __shfl_xor(x, 16, 64));
  x = fmaxf(x, __shfl_xor(x, 32, 64));
#endif
  return x;
}

// ------- prepass (merged): z=0: K fp32->bf16; z=1: V -> V^T bf16 -------
// V^T columns permuted within each 64-tile: position p holds element
// k(p) = 32*(p>>5) + 16*((p>>2)&1) + 4*((p>>3)&3) + (p&3), so the PV
// A-fragment {k=32t2+4g+i} u {k=32t2+16+4g+i} is contiguous 16B at p=32t2+8g.
__global__ __launch_bounds__(256) void prep(const float* __restrict__ K,
                                            const float* __restrict__ V,
                                            short* __restrict__ Kb,
                                            short* __restrict__ Vt) {
  const int tile = blockIdx.x, bh = blockIdx.y;
  const int tid = threadIdx.x;
  const int r = tid >> 2, c = (tid & 3) * 16;
  const size_t base = (size_t)bh * Sn * Dn;

  if (blockIdx.z == 0) {
    const float* kp = K + base + (size_t)(tile * 64 + r) * Dn + c;
    float4 x0 = *(const float4*)(kp + 0);
    float4 x1 = *(const float4*)(kp + 4);
    float4 x2 = *(const float4*)(kp + 8);
    float4 x3 = *(const float4*)(kp + 12);
    bf16x8 w0, w1;
    w0[0] = f2bf(x0.x); w0[1] = f2bf(x0.y); w0[2] = f2bf(x0.z); w0[3] = f2bf(x0.w);
    w0[4] = f2bf(x1.x); w0[5] = f2bf(x1.y); w0[6] = f2bf(x1.z); w0[7] = f2bf(x1.w);
    w1[0] = f2bf(x2.x); w1[1] = f2bf(x2.y); w1[2] = f2bf(x2.z); w1[3] = f2bf(x2.w);
    w1[4] = f2bf(x3.x); w1[5] = f2bf(x3.y); w1[6] = f2bf(x3.z); w1[7] = f2bf(x3.w);
    short* op = Kb + base + (size_t)(tile * 64 + r) * Dn + c;
    *(bf16x8*)op = w0;
    *(bf16x8*)(op + 8) = w1;
  } else {
    __shared__ short t[64][66];  // +2 pad
    const float* vp = V + base + (size_t)(tile * 64 + r) * Dn + c;
    float4 x0 = *(const float4*)(vp + 0);
    float4 x1 = *(const float4*)(vp + 4);
    float4 x2 = *(const float4*)(vp + 8);
    float4 x3 = *(const float4*)(vp + 12);
    short* tr = &t[r][c];
    tr[0] = f2bf(x0.x); tr[1] = f2bf(x0.y); tr[2] = f2bf(x0.z); tr[3] = f2bf(x0.w);
    tr[4] = f2bf(x1.x); tr[5] = f2bf(x1.y); tr[6] = f2bf(x1.z); tr[7] = f2bf(x1.w);
    tr[8] = f2bf(x2.x); tr[9] = f2bf(x2.y); tr[10] = f2bf(x2.z); tr[11] = f2bf(x2.w);
    tr[12] = f2bf(x3.x); tr[13] = f2bf(x3.y); tr[14] = f2bf(x3.z); tr[15] = f2bf(x3.w);
    __syncthreads();
    short* op = Vt + base + (size_t)r * Sn + tile * 64 + c;
    bf16x8 w0, w1;
#pragma unroll
    for (int j = 0; j < 8; ++j) {
      int p0 = c + j, p1 = c + 8 + j;
      int k0 = 32 * (p0 >> 5) + 16 * ((p0 >> 2) & 1) + 4 * ((p0 >> 3) & 3) + (p0 & 3);
      int k1 = 32 * (p1 >> 5) + 16 * ((p1 >> 2) & 1) + 4 * ((p1 >> 3) & 3) + (p1 & 3);
      w0[j] = t[k0][r];
      w1[j] = t[k1][r];
    }
    *(bf16x8*)op = w0;
    *(bf16x8*)(op + 8) = w1;
  }
}

// ---------------------------- main attention ----------------------------
__global__ __launch_bounds__(256, 4) void attn_fwd(
    const float* __restrict__ Q, const short* __restrict__ Kb,
    const short* __restrict__ Vt, const float* __restrict__ SF,
    float* __restrict__ O) {
  __shared__ short Kbuf[2][64 * 64];   // [k][d] bf16, swizzled
  __shared__ short Vbuf[2][64 * 64];   // [d][p(k)] bf16, swizzled

  const int bh = blockIdx.x;
  const int qt = (gridDim.y - 1) - blockIdx.y;  // heavy-first
  const int tid = threadIdx.x;
  const int wave = tid >> 6, lane = tid & 63;
  const int g = lane >> 4, lc = lane & 15;
  const float qscale = 1.4426950408889634f / SF[0];  // exp2 domain

  const size_t base = (size_t)bh * Sn * Dn;
  const int qg = qt * QBLK + wave * 16 + lc;  // this lane's q row

  // hoisted per-lane fragment LDS offsets (loop-invariant)
  int ka[4][2], va[2][4];
#pragma unroll
  for (int t = 0; t < 4; ++t) {
    ka[t][0] = swz(t * 16 + lc, g * 16);
    ka[t][1] = swz(t * 16 + lc, g * 16 + 64);
  }
#pragma unroll
  for (int t2 = 0; t2 < 2; ++t2)
#pragma unroll
    for (int dt = 0; dt < 4; ++dt)
      va[t2][dt] = swz(dt * 16 + lc, t2 * 64 + g * 16);
  // hoisted staging source offsets (within a tile)
  int koff[2], voff[2];
#pragma unroll
  for (int j = 0; j < 2; ++j) {
    int c = wave * 2 + j;
    int off = c * 1024 + lane * 16;
    int row = off >> 7;
    int col = (off & 127) ^ ((row & 7) << 4);
    koff[j] = row * 128 + col;
    voff[j] = row * (Sn * 2) + col;
  }

  // strength-reduced staging source pointers (advance per staged tile)
  const char* kpg = (const char*)(Kb + base);
  const char* vpg = (const char*)(Vt + base);

  auto stageK = [&](int buf) {
#pragma unroll
    for (int j = 0; j < 2; ++j)
      gl2lds16(kpg + koff[j], (char*)Kbuf[buf] + (wave * 2 + j) * 1024);
    kpg += KBLK * Dn * 2;
  };
  auto stageV = [&](int buf) {
#pragma unroll
    for (int j = 0; j < 2; ++j)
      gl2lds16(vpg + voff[j], (char*)Vbuf[buf] + (wave * 2 + j) * 1024);
    vpg += KBLK * 2;
  };

  // ---- Q fragment (B operand): elem j = Q[qg][g*8+32h+j] * qscale ----
  bf16x8 bq[2];
  {
    const float* qp = Q + base + (size_t)qg * Dn + g * 8;
#pragma unroll
    for (int h = 0; h < 2; ++h) {
      float4 x0 = *(const float4*)(qp + 32 * h);
      float4 x1 = *(const float4*)(qp + 32 * h + 4);
      bf16x8 a;
      a[0] = f2bf(x0.x * qscale); a[1] = f2bf(x0.y * qscale);
      a[2] = f2bf(x0.z * qscale); a[3] = f2bf(x0.w * qscale);
      a[4] = f2bf(x1.x * qscale); a[5] = f2bf(x1.y * qscale);
      a[6] = f2bf(x1.z * qscale); a[7] = f2bf(x1.w * qscale);
      bq[h] = a;
    }
  }

  // all-ones A-fragment for the l-accumulating MFMA (bf16 1.0 = 0x3F80)
  bf16x8 ones;
#pragma unroll
  for (int j = 0; j < 8; ++j) ones[j] = (short)0x3F80;

  f32x4 o[4], lsum = (f32x4){0.f, 0.f, 0.f, 0.f};
#pragma unroll
  for (int dt = 0; dt < 4; ++dt) o[dt] = (f32x4){0.f, 0.f, 0.f, 0.f};
  float m = -10000.0f;  // finite sentinel; first tile always rescales

  const int nt = qt + 1;
  int cur = 0;
  stageK(0);
  stageV(0);
  __syncthreads();

  for (int kt = 0; kt < nt; ++kt) {
    if (kt + 1 < nt) { stageK(cur ^ 1); stageV(cur ^ 1); }

    const char* Kc = (const char*)Kbuf[cur];
    const char* Vc = (const char*)Vbuf[cur];

    // ---- swapped QK^T: s[t][i] = S[q=qg][k = kb+t*16+g*4+i] ----
    f32x4 s[4];
    __builtin_amdgcn_s_setprio(1);
#pragma unroll
    for (int t = 0; t < 4; ++t) {
      bf16x8 ak0 = *(const bf16x8*)(Kc + ka[t][0]);
      bf16x8 ak1 = *(const bf16x8*)(Kc + ka[t][1]);
      f32x4 z = (f32x4){0.f, 0.f, 0.f, 0.f};
      z = MFMA32K(ak0, bq[0], z);
      z = MFMA32K(ak1, bq[1], z);
      s[t] = z;
    }
    __builtin_amdgcn_s_setprio(0);

    if (kt == qt) {  // causal mask on diagonal tile only
      const int kb = kt * KBLK;
#pragma unroll
      for (int t = 0; t < 4; ++t)
#pragma unroll
        for (int i = 0; i < 4; ++i) {
          int kg = kb + t * 16 + g * 4 + i;
          if (kg > qg) s[t][i] = -30000.0f;
        }
    }

    // ---- in-register online softmax (exp2 domain), defer-max THR=8 ----
    float pmax = fmaxf(fmaxf(s[0][0], s[0][1]), fmaxf(s[0][2], s[0][3]));
#pragma unroll
    for (int t = 1; t < 4; ++t)
      pmax = fmaxf(pmax, fmaxf(fmaxf(s[t][0], s[t][1]),
                               fmaxf(s[t][2], s[t][3])));
    pmax = xred_max(pmax);
    if (!__all(pmax - m <= 8.0f)) {
      float mnew = fmaxf(m, pmax);
      float alpha = EXP2(m - mnew);
      lsum[0] *= alpha;  // only [0] is ever read
#pragma unroll
      for (int dt = 0; dt < 4; ++dt) o[dt] *= alpha;
      m = mnew;
    }
#pragma unroll
    for (int t = 0; t < 4; ++t)
#pragma unroll
      for (int i = 0; i < 4; ++i) s[t][i] = EXP2(s[t][i] - m);

    // ---- pack P; PV + l via MFMA (ones-column), zero-conflict b128 ----
    union { unsigned uu[4]; bf16x8 v; } pb[2];
#pragma unroll
    for (int t2 = 0; t2 < 2; ++t2) {
      pb[t2].uu[0] = pk_bf16(s[2 * t2][0], s[2 * t2][1]);
      pb[t2].uu[1] = pk_bf16(s[2 * t2][2], s[2 * t2][3]);
      pb[t2].uu[2] = pk_bf16(s[2 * t2 + 1][0], s[2 * t2 + 1][1]);
      pb[t2].uu[3] = pk_bf16(s[2 * t2 + 1][2], s[2 * t2 + 1][3]);
    }
    __builtin_amdgcn_s_setprio(1);
#pragma unroll
    for (int t2 = 0; t2 < 2; ++t2) {
      lsum = MFMA32K(ones, pb[t2].v, lsum);
#pragma unroll
      for (int dt = 0; dt < 4; ++dt) {
        bf16x8 av = *(const bf16x8*)(Vc + va[t2][dt]);
        o[dt] = MFMA32K(av, pb[t2].v, o[dt]);
      }
    }
    __builtin_amdgcn_s_setprio(0);

    __syncthreads();  // next tile landed (vmcnt) + cur fully consumed
    cur ^= 1;
  }

  // ---- epilogue: O[q][d] = o / l, coalesced f32x4 stores ----
  const float inv = 1.0f / lsum[0];
  float* op = O + base + (size_t)qg * Dn;
#pragma unroll
  for (int dt = 0; dt < 4; ++dt) {
    f32x4 r = o[dt] * inv;
    *(f32x4*)(op + dt * 16 + g * 4) = r;
  }
}

extern "C" void kernel_launch(void* const* d_in, const int* in_sizes, int n_in,
                              void* d_out, int out_size, void* d_ws, size_t ws_size,
                              hipStream_t stream) {
  const float* Q = (const float*)d_in[0];
  const float* K = (const float*)d_in[1];
  const float* V = (const float*)d_in[2];
  const float* SF = (const float*)d_in[3];
  // d_in[4] causal mask: tril by construction -> applied analytically (k<=q).
  float* O = (float*)d_out;

  short* Kb = (short*)d_ws;  // [B*H][2048][64] bf16
  short* Vt = Kb + NE;       // [B*H][64][2048] bf16 (column-permuted per tile)

  prep<<<dim3(Sn / 64, Bsz * Hn, 2), 256, 0, stream>>>(K, V, Kb, Vt);
  attn_fwd<<<dim3(Bsz * Hn, Sn / QBLK), 256, 0, stream>>>(Q, Kb, Vt, SF, O);
}